// Round 10
// baseline (396.481 us; speedup 1.0000x reference)
//
#include <hip/hip_runtime.h>
#include <cstdint>
#include <cstddef>

typedef __attribute__((ext_vector_type(8))) short short8;
typedef __attribute__((ext_vector_type(4))) float f32x4;
typedef __attribute__((ext_vector_type(2))) float f32x2;

#define NBLK 512        // edge-chunk blocks for hist/scatter (pow2, = 8 XCDs * 64)
#define NBLK_SHIFT 9

__device__ inline int chunk_of_block(int bid) { return ((bid & 7) << 6) | (bid >> 3); }

__device__ inline unsigned short f2bf(float f) {
  union { float f; unsigned int u; } x; x.f = f;
  unsigned int r = x.u + 0x7FFFu + ((x.u >> 16) & 1u);  // round-to-nearest-even
  return (unsigned short)(r >> 16);
}
__device__ inline float bf2f(unsigned short s) {
  union { unsigned int u; float f; } x; x.u = ((unsigned int)s) << 16;
  return x.f;
}

// ---------------- P1: per-block bucket histogram (LDS atomics only) ----------------
// blocks 0..2 transpose W1..W3; block 3 zeroes the per-plane gather zero-rows of A8.

__global__ __launch_bounds__(256) void hist_kernel(const int* __restrict__ cols,
                                                   int* __restrict__ histG,
                                                   const int* __restrict__ labels,
                                                   float* __restrict__ labelsum,
                                                   const float* __restrict__ W1,
                                                   const float* __restrict__ W2,
                                                   const float* __restrict__ W3,
                                                   unsigned short* __restrict__ Wt1,
                                                   unsigned short* __restrict__ Wt2,
                                                   unsigned short* __restrict__ Wt3,
                                                   unsigned char* __restrict__ zbase,
                                                   size_t PS8,
                                                   int E, int N, int NBUCK) {
  __shared__ int h[512];
  if (blockIdx.x < 3) {
    const float* W; unsigned short* Wt; int K;
    if (blockIdx.x == 0)      { W = W1; Wt = Wt1; K = 128; }
    else if (blockIdx.x == 1) { W = W2; Wt = Wt2; K = 64; }
    else                      { W = W3; Wt = Wt3; K = 64; }
    int total = K * 64;
    for (int i = threadIdx.x; i < total; i += 256) {
      int n = i / K, k = i - n * K;  // Wt[n][k] = W[k][n]
      Wt[i] = f2bf(W[k * 64 + n]);
    }
  } else if (blockIdx.x == 3 && threadIdx.x < 8) {
    *(unsigned long long*)(zbase + (size_t)threadIdx.x * PS8) = 0ull;  // plane zero-rows
  }
  {
    int chunkL = (N + NBLK - 1) / NBLK;
    int ls = blockIdx.x * chunkL;
    int le = min(N, ls + chunkL);
    float v = 0.f;
    for (int i = ls + threadIdx.x; i < le; i += 256) v += (float)labels[i];
#pragma unroll
    for (int o = 32; o > 0; o >>= 1) v += __shfl_down(v, o);
    __shared__ float sl[4];
    if ((threadIdx.x & 63) == 0) sl[threadIdx.x >> 6] = v;
    __syncthreads();
    if (threadIdx.x == 0) labelsum[blockIdx.x] = sl[0] + sl[1] + sl[2] + sl[3];
  }
  for (int i = threadIdx.x; i < NBUCK; i += 256) h[i] = 0;
  __syncthreads();
  int cchunk = chunk_of_block(blockIdx.x);
  int chunk = (E + NBLK - 1) / NBLK;
  int s = cchunk * chunk;
  int e = min(E, s + chunk);
  for (int i = s + threadIdx.x; i < e; i += 256) atomicAdd(&h[cols[i] >> 8], 1);
  __syncthreads();
  for (int i = threadIdx.x; i < NBUCK; i += 256)
    histG[cchunk * NBUCK + i] = h[i];
}

// ---------------- P2: scan of NBUCK*NBLK counts, bucket-major logical order ----------------

__global__ __launch_bounds__(256) void scan_partials_t(const int* __restrict__ histG,
                                                       int* __restrict__ partials,
                                                       int total, int NBUCK) {
  int i = blockIdx.x * 256 + threadIdx.x;
  int v = 0;
  if (i < total) {
    int bucket = i >> NBLK_SHIFT, blk = i & (NBLK - 1);
    v = histG[blk * NBUCK + bucket];
  }
#pragma unroll
  for (int o = 32; o > 0; o >>= 1) v += __shfl_down(v, o);
  __shared__ int s[4];
  if ((threadIdx.x & 63) == 0) s[threadIdx.x >> 6] = v;
  __syncthreads();
  if (threadIdx.x == 0) partials[blockIdx.x] = s[0] + s[1] + s[2] + s[3];
}

__global__ __launch_bounds__(256) void scan_block(int* __restrict__ partials, int nb,
                                                  float* __restrict__ loss,
                                                  const float* __restrict__ labelsum,
                                                  float* __restrict__ pmsum) {
  __shared__ int tmp[256];
  __shared__ int carry;
  int tid = threadIdx.x;
  {
    float v = 0.f;
    for (int i = tid; i < NBLK; i += 256) v += labelsum[i];
#pragma unroll
    for (int o = 32; o > 0; o >>= 1) v += __shfl_down(v, o);
    __shared__ float sl[4];
    if ((tid & 63) == 0) sl[tid >> 6] = v;
    __syncthreads();
    if (tid == 0) *pmsum = sl[0] + sl[1] + sl[2] + sl[3];
  }
  if (tid == 0) { carry = 0; *loss = 0.f; }
  __syncthreads();
  for (int base = 0; base < nb; base += 256) {
    int i = base + tid;
    int v = (i < nb) ? partials[i] : 0;
    tmp[tid] = v;
    __syncthreads();
    int incl = v;
    for (int o = 1; o < 256; o <<= 1) {
      int t = (tid >= o) ? tmp[tid - o] : 0;
      __syncthreads();
      incl += t;
      tmp[tid] = incl;
      __syncthreads();
    }
    int total = tmp[255];
    int c = carry;
    if (i < nb) partials[i] = c + incl - v;  // exclusive
    __syncthreads();
    if (tid == 0) carry = c + total;
    __syncthreads();
  }
}

__global__ __launch_bounds__(256) void scan_final_t(const int* __restrict__ histG,
                                                    const int* __restrict__ partials,
                                                    int* __restrict__ scannedG,
                                                    int total, int NBUCK) {
  __shared__ int tmp[256];
  int tid = threadIdx.x;
  int i = blockIdx.x * 256 + tid;
  int bucket = i >> NBLK_SHIFT, blk = i & (NBLK - 1);
  int v = (i < total) ? histG[blk * NBUCK + bucket] : 0;
  tmp[tid] = v;
  __syncthreads();
  int incl = v;
  for (int o = 1; o < 256; o <<= 1) {
    int t = (tid >= o) ? tmp[tid - o] : 0;
    __syncthreads();
    incl += t;
    tmp[tid] = incl;
    __syncthreads();
  }
  if (i < total) scannedG[blk * NBUCK + bucket] = partials[blockIdx.x] + incl - v;
}

// ---------------- P3: bucket-partition scatter (LDS cursors, no global atomics) ----------------

__global__ __launch_bounds__(256) void scatter_kernel(const int* __restrict__ rows,
                                                      const int* __restrict__ cols,
                                                      const int* __restrict__ scannedG,
                                                      unsigned int* __restrict__ packed,
                                                      int E, int NBUCK) {
  __shared__ int cur[512];
  int cchunk = chunk_of_block(blockIdx.x);
  for (int i = threadIdx.x; i < NBUCK; i += 256)
    cur[i] = scannedG[cchunk * NBUCK + i];
  __syncthreads();
  int chunk = (E + NBLK - 1) / NBLK;
  int s = cchunk * chunk;
  int e = min(E, s + chunk);
  for (int i = s + threadIdx.x; i < e; i += 256) {
    int c = cols[i];
    int r = rows[i];
    int pos = atomicAdd(&cur[c >> 8], 1);
    packed[pos] = ((unsigned int)(c & 255) << 24) | (unsigned int)r;
  }
}

// ---------------- P4: per-bucket CSR finalize + FUSED layer-1 GEMM (plane output) ----------------

__global__ __launch_bounds__(1024) void csr_finalize_gemm1(const unsigned int* __restrict__ packed,
                                                           const int* __restrict__ scannedG,
                                                           int* __restrict__ sorted_src,
                                                           int* __restrict__ offsets,
                                                           float* __restrict__ dinv,
                                                           const float* __restrict__ xv,
                                                           const unsigned short* __restrict__ Wt,
                                                           unsigned char* __restrict__ A8out,
                                                           int N, int E, int NBUCK, size_t PS8) {
  __shared__ int h[256];
  __shared__ int tmp[256];
  __shared__ int cur[256];
  __shared__ float sdinv[256];
  __shared__ unsigned short gtile[16][16 * 72];
  int b = blockIdx.x;
  int tid = threadIdx.x;
  int base = scannedG[b];
  int end = (b + 1 < NBUCK) ? scannedG[b + 1] : E;
  if (tid < 256) h[tid] = 0;
  __syncthreads();
  for (int i = base + tid; i < end; i += 1024)
    atomicAdd(&h[packed[i] >> 24], 1);
  __syncthreads();
  if (tid < 256) {
    int v = h[tid];
    tmp[tid] = v;
  }
  __syncthreads();
  if (tid < 256) {
    int v = h[tid];
    int incl = v;
    for (int o = 1; o < 256; o <<= 1) {
      int t = (tid >= o) ? tmp[tid - o] : 0;
      __syncthreads();
      incl += t;
      tmp[tid] = incl;
      __syncthreads();
    }
    int excl = incl - v;
    int node = b * 256 + tid;
    float dv = rsqrtf((float)(v + 1));  // +1 self loop
    if (node < N) {
      offsets[node] = base + excl;
      dinv[node] = dv;
    }
    sdinv[tid] = dv;
    cur[tid] = base + excl;
    if (b == NBUCK - 1 && tid == 0) offsets[N] = E;
  } else {
    for (int o = 1; o < 256; o <<= 1) { __syncthreads(); __syncthreads(); }
  }
  __syncthreads();
  for (int i = base + tid; i < end; i += 1024) {
    unsigned int p = packed[i];
    int pos = atomicAdd(&cur[p >> 24], 1);
    sorted_src[pos] = (int)(p & 0xFFFFFFu);
  }
  // ---- fused layer-1 GEMM for this bucket's 256 nodes ----
  {
    const int K = 128;
    int wv = tid >> 6;                 // wave 0..15
    int lane = tid & 63;
    int m = lane & 15, quad = lane >> 4;
    int lrow0 = wv * 16;
    int m0 = b * 256 + lrow0;
    int rowA = m0 + m;
    bool rowOK = rowA < N;
    f32x4 acc[4] = {{0.f,0.f,0.f,0.f},{0.f,0.f,0.f,0.f},{0.f,0.f,0.f,0.f},{0.f,0.f,0.f,0.f}};
#pragma unroll
    for (int kc = 0; kc < K / 32; ++kc) {
      short8 a = {0, 0, 0, 0, 0, 0, 0, 0};
      if (rowOK) {
        const float* hp = xv + (size_t)rowA * K + kc * 32 + quad * 8;
        float4 p0 = ((const float4*)hp)[0];
        float4 p1 = ((const float4*)hp)[1];
        a[0] = (short)f2bf(p0.x); a[1] = (short)f2bf(p0.y);
        a[2] = (short)f2bf(p0.z); a[3] = (short)f2bf(p0.w);
        a[4] = (short)f2bf(p1.x); a[5] = (short)f2bf(p1.y);
        a[6] = (short)f2bf(p1.z); a[7] = (short)f2bf(p1.w);
      }
#pragma unroll
      for (int t = 0; t < 4; ++t) {
        short8 bb = *(const short8*)(Wt + (size_t)(t * 16 + m) * K + kc * 32 + quad * 8);
        acc[t] = __builtin_amdgcn_mfma_f32_16x16x32_bf16(a, bb, acc[t], 0, 0, 0);
      }
    }
    unsigned short* tw = gtile[wv];
#pragma unroll
    for (int r = 0; r < 4; ++r) {
      int row = quad * 4 + r;
      float dv = sdinv[lrow0 + row];
#pragma unroll
      for (int t = 0; t < 4; ++t)
        tw[row * 72 + t * 16 + m] = f2bf(acc[t][r] * dv);
    }
  }
  __syncthreads();
  // pack epilogue: 256 rows x 8 planes = 2048 items, uint2 per item, coalesced per plane
#pragma unroll
  for (int u = 0; u < 2; ++u) {
    int id = u * 1024 + tid;
    int plane = id >> 8, row = id & 255;
    int gr = b * 256 + row;
    if (gr < N) {
      const unsigned int* s4 = (const unsigned int*)(gtile[row >> 4] + (row & 15) * 72 + plane * 8);
      float f0 = bf2f((unsigned short)(s4[0] & 0xFFFFu));
      float f1 = bf2f((unsigned short)(s4[0] >> 16));
      float f2 = bf2f((unsigned short)(s4[1] & 0xFFFFu));
      float f3 = bf2f((unsigned short)(s4[1] >> 16));
      float f4 = bf2f((unsigned short)(s4[2] & 0xFFFFu));
      float f5 = bf2f((unsigned short)(s4[2] >> 16));
      float f6 = bf2f((unsigned short)(s4[3] & 0xFFFFu));
      float f7 = bf2f((unsigned short)(s4[3] >> 16));
      int pk0 = 0, pk1 = 0;
      pk0 = __builtin_amdgcn_cvt_pk_fp8_f32(f0, f1, pk0, false);
      pk0 = __builtin_amdgcn_cvt_pk_fp8_f32(f2, f3, pk0, true);
      pk1 = __builtin_amdgcn_cvt_pk_fp8_f32(f4, f5, pk1, false);
      pk1 = __builtin_amdgcn_cvt_pk_fp8_f32(f6, f7, pk1, true);
      uint2 o; o.x = (unsigned int)pk0; o.y = (unsigned int)pk1;
      *(uint2*)(A8out + (size_t)plane * PS8 + (size_t)gr * 8) = o;
    }
  }
}

// ---------------- agg_plane: gather-aggregate ONE 8-feature plane per block ----------------
// plane = blockIdx % 8 -> XCD round-robin pins each 0.8 MB plane to one XCD's L2.
// One node per 4-lane quad; each lane owns 4 edges/batch (branchless, ZR-clamped),
// 8-B gathers from the L2-resident plane; quad shfl-reduce; bias+ReLU; bf16 H-plane out.

__global__ __launch_bounds__(256) void agg_plane(const unsigned char* __restrict__ A8,
                                                 const int* __restrict__ offsets,
                                                 const int* __restrict__ sorted_src,
                                                 const float* __restrict__ dinv,
                                                 const float* __restrict__ bias,
                                                 unsigned short* __restrict__ Hp,
                                                 int N, int ZR, size_t PS8, size_t PSHe) {
  int p = blockIdx.x & 7;
  int chunk = blockIdx.x >> 3;
  int lane = threadIdx.x & 63;
  int cl = threadIdx.x >> 2;
  int c = chunk * 64 + cl;
  if (c >= N) return;
  int l4 = lane & 3;
  const unsigned char* P = A8 + (size_t)p * PS8;
  int s = offsets[c], e = offsets[c + 1];
  float dc = dinv[c];
  uint2 svr = *(const uint2*)(P + (size_t)c * 8);
  f32x2 a0 = {0.f, 0.f}, a1 = {0.f, 0.f}, a2 = {0.f, 0.f}, a3 = {0.f, 0.f};
  for (int base = s; base < e; base += 16) {
    int i0 = base + l4 * 4;
    int r0 = (i0     < e) ? sorted_src[i0]     : ZR;
    int r1 = (i0 + 1 < e) ? sorted_src[i0 + 1] : ZR;
    int r2 = (i0 + 2 < e) ? sorted_src[i0 + 2] : ZR;
    int r3 = (i0 + 3 < e) ? sorted_src[i0 + 3] : ZR;
    uint2 v0 = *(const uint2*)(P + (size_t)(unsigned int)r0 * 8);
    uint2 v1 = *(const uint2*)(P + (size_t)(unsigned int)r1 * 8);
    uint2 v2 = *(const uint2*)(P + (size_t)(unsigned int)r2 * 8);
    uint2 v3 = *(const uint2*)(P + (size_t)(unsigned int)r3 * 8);
    __builtin_amdgcn_sched_barrier(0);
    a0 += __builtin_amdgcn_cvt_pk_f32_fp8((int)v0.x, false);
    a1 += __builtin_amdgcn_cvt_pk_f32_fp8((int)v0.x, true);
    a2 += __builtin_amdgcn_cvt_pk_f32_fp8((int)v0.y, false);
    a3 += __builtin_amdgcn_cvt_pk_f32_fp8((int)v0.y, true);
    a0 += __builtin_amdgcn_cvt_pk_f32_fp8((int)v1.x, false);
    a1 += __builtin_amdgcn_cvt_pk_f32_fp8((int)v1.x, true);
    a2 += __builtin_amdgcn_cvt_pk_f32_fp8((int)v1.y, false);
    a3 += __builtin_amdgcn_cvt_pk_f32_fp8((int)v1.y, true);
    a0 += __builtin_amdgcn_cvt_pk_f32_fp8((int)v2.x, false);
    a1 += __builtin_amdgcn_cvt_pk_f32_fp8((int)v2.x, true);
    a2 += __builtin_amdgcn_cvt_pk_f32_fp8((int)v2.y, false);
    a3 += __builtin_amdgcn_cvt_pk_f32_fp8((int)v2.y, true);
    a0 += __builtin_amdgcn_cvt_pk_f32_fp8((int)v3.x, false);
    a1 += __builtin_amdgcn_cvt_pk_f32_fp8((int)v3.x, true);
    a2 += __builtin_amdgcn_cvt_pk_f32_fp8((int)v3.y, false);
    a3 += __builtin_amdgcn_cvt_pk_f32_fp8((int)v3.y, true);
  }
  float acc[8] = {a0[0], a0[1], a1[0], a1[1], a2[0], a2[1], a3[0], a3[1]};
#pragma unroll
  for (int q = 0; q < 8; ++q) {
    acc[q] += __shfl_xor(acc[q], 1);
    acc[q] += __shfl_xor(acc[q], 2);
  }
  if (l4 == 0) {
    f32x2 s0 = __builtin_amdgcn_cvt_pk_f32_fp8((int)svr.x, false);
    f32x2 s1 = __builtin_amdgcn_cvt_pk_f32_fp8((int)svr.x, true);
    f32x2 s2 = __builtin_amdgcn_cvt_pk_f32_fp8((int)svr.y, false);
    f32x2 s3 = __builtin_amdgcn_cvt_pk_f32_fp8((int)svr.y, true);
    acc[0] += s0[0]; acc[1] += s0[1]; acc[2] += s1[0]; acc[3] += s1[1];
    acc[4] += s2[0]; acc[5] += s2[1]; acc[6] += s3[0]; acc[7] += s3[1];
    const float* bp = bias + p * 8;
    short8 ov;
#pragma unroll
    for (int q = 0; q < 8; ++q) {
      float v = fmaf(acc[q], dc, bp[q]);
      ov[q] = (short)f2bf(v > 0.f ? v : 0.f);
    }
    *(short8*)(Hp + (size_t)p * PSHe + (size_t)c * 8) = ov;
  }
}

// ---------------- gemm_mid: A8planes = (Hplanes @ W) * dinv, 64 rows/block ----------------

__global__ __launch_bounds__(256) void gemm_mid(const unsigned short* __restrict__ Hp,
                                                const unsigned short* __restrict__ Wt,
                                                const float* __restrict__ dinv,
                                                unsigned char* __restrict__ A8out,
                                                int N, size_t PSHe, size_t PS8) {
  __shared__ unsigned short hl[64 * 72];
  int lane = threadIdx.x & 63, wv = threadIdx.x >> 6;
  int m = lane & 15, quad = lane >> 4;
  int rbase = wv * 16;
  int m0 = blockIdx.x * 64;
  int rowA = m0 + rbase + m;
  bool rowOK = rowA < N;
  f32x4 acc[4] = {{0.f,0.f,0.f,0.f},{0.f,0.f,0.f,0.f},{0.f,0.f,0.f,0.f},{0.f,0.f,0.f,0.f}};
#pragma unroll
  for (int kc = 0; kc < 2; ++kc) {
    short8 a = {0, 0, 0, 0, 0, 0, 0, 0};
    if (rowOK)
      a = *(const short8*)(Hp + (size_t)(kc * 4 + quad) * PSHe + (size_t)rowA * 8);
#pragma unroll
    for (int t = 0; t < 4; ++t) {
      short8 b = *(const short8*)(Wt + (size_t)(t * 16 + m) * 64 + kc * 32 + quad * 8);
      acc[t] = __builtin_amdgcn_mfma_f32_16x16x32_bf16(a, b, acc[t], 0, 0, 0);
    }
  }
#pragma unroll
  for (int r = 0; r < 4; ++r) {
    int row = rbase + quad * 4 + r;
    int gr = m0 + row;
    float dv = dinv[gr < N ? gr : 0];
#pragma unroll
    for (int t = 0; t < 4; ++t)
      hl[row * 72 + t * 16 + m] = f2bf(acc[t][r] * dv);
  }
  __syncthreads();
  // pack: 64 rows x 8 planes = 512 items, uint2 per item
#pragma unroll
  for (int u = 0; u < 2; ++u) {
    int id = u * 256 + threadIdx.x;
    int plane = id >> 6, row = id & 63;
    int gr = m0 + row;
    if (gr < N) {
      const unsigned int* s4 = (const unsigned int*)(hl + row * 72 + plane * 8);
      float f0 = bf2f((unsigned short)(s4[0] & 0xFFFFu));
      float f1 = bf2f((unsigned short)(s4[0] >> 16));
      float f2 = bf2f((unsigned short)(s4[1] & 0xFFFFu));
      float f3 = bf2f((unsigned short)(s4[1] >> 16));
      float f4 = bf2f((unsigned short)(s4[2] & 0xFFFFu));
      float f5 = bf2f((unsigned short)(s4[2] >> 16));
      float f6 = bf2f((unsigned short)(s4[3] & 0xFFFFu));
      float f7 = bf2f((unsigned short)(s4[3] >> 16));
      int pk0 = 0, pk1 = 0;
      pk0 = __builtin_amdgcn_cvt_pk_fp8_f32(f0, f1, pk0, false);
      pk0 = __builtin_amdgcn_cvt_pk_fp8_f32(f2, f3, pk0, true);
      pk1 = __builtin_amdgcn_cvt_pk_fp8_f32(f4, f5, pk1, false);
      pk1 = __builtin_amdgcn_cvt_pk_fp8_f32(f6, f7, pk1, true);
      uint2 o; o.x = (unsigned int)pk0; o.y = (unsigned int)pk1;
      *(uint2*)(A8out + (size_t)plane * PS8 + (size_t)gr * 8) = o;
    }
  }
}

// ---------------- MLP head + sigmoid + weighted BCE loss (bf16 H planes) ----------------

__global__ __launch_bounds__(256) void head_loss_kernel(const unsigned short* __restrict__ Hp,
                                                        const float* __restrict__ lW1,
                                                        const float* __restrict__ lb1,
                                                        const float* __restrict__ lW2,
                                                        const float* __restrict__ lb2,
                                                        const int* __restrict__ labels,
                                                        const float* __restrict__ pmsum,
                                                        float* __restrict__ p,
                                                        float* __restrict__ loss,
                                                        int N, size_t PSHe) {
  int n = blockIdx.x * 256 + threadIdx.x;
  float contrib = 0.f;
  if (n < N) {
    float acc[8];
#pragma unroll
    for (int j = 0; j < 8; ++j) acc[j] = lb1[j];
#pragma unroll
    for (int ch = 0; ch < 8; ++ch) {
      short8 hv8 = *(const short8*)(Hp + (size_t)ch * PSHe + (size_t)n * 8);
#pragma unroll
      for (int q = 0; q < 8; ++q) {
        float v = bf2f((unsigned short)hv8[q]);
        int k = ch * 8 + q;
#pragma unroll
        for (int j = 0; j < 8; ++j) acc[j] = fmaf(v, lW1[k * 8 + j], acc[j]);
      }
    }
    float s = lb2[0];
#pragma unroll
    for (int j = 0; j < 8; ++j) {
      float a = acc[j] > 0.f ? acc[j] : 0.f;
      s = fmaf(a, lW2[j], s);
    }
    float pv = 1.0f / (1.0f + expf(-s));
    p[n] = pv;
    float pm = *pmsum / (float)N;
    float y = (float)labels[n];
    float w = y * (1.f - pm) + (1.f - y) * pm;
    float pc = fminf(fmaxf(pv, 1e-7f), 1.f - 1e-7f);
    float bce = -(y * logf(pc) + (1.f - y) * logf(1.f - pc));
    contrib = w * bce / (float)N;
  }
#pragma unroll
  for (int o = 32; o > 0; o >>= 1) contrib += __shfl_down(contrib, o);
  __shared__ float sh[4];
  int lane = threadIdx.x & 63, wv = threadIdx.x >> 6;
  if (lane == 0) sh[wv] = contrib;
  __syncthreads();
  if (threadIdx.x == 0) atomicAdd(loss, sh[0] + sh[1] + sh[2] + sh[3]);
}

// ---------------- launch ----------------

extern "C" void kernel_launch(void* const* d_in, const int* in_sizes, int n_in,
                              void* d_out, int out_size, void* d_ws, size_t ws_size,
                              hipStream_t stream) {
  const float* x      = (const float*)d_in[0];
  const int*   ei     = (const int*)d_in[1];
  const int*   labels = (const int*)d_in[2];
  const float* W1 = (const float*)d_in[3];
  const float* b1 = (const float*)d_in[4];
  const float* W2 = (const float*)d_in[5];
  const float* b2 = (const float*)d_in[6];
  const float* W3 = (const float*)d_in[7];
  const float* b3 = (const float*)d_in[8];
  const float* lW1 = (const float*)d_in[9];
  const float* lb1 = (const float*)d_in[10];
  const float* lW2 = (const float*)d_in[11];
  const float* lb2 = (const float*)d_in[12];

  int N = in_sizes[2];            // labels: [N,1]
  int E = in_sizes[1] / 2;        // edge_index: [2,E]
  const int* rows = ei;           // sources
  const int* cols = ei + E;       // targets (aggregation)

  int Npad = (N + 63) & ~63;
  int NpadZ = Npad + 32;                    // + zero-row & pad
  int NBUCK = (N + 255) >> 8;               // 256-node buckets
  int totalH = NBUCK * NBLK;                // histogram entries
  int nb2 = (totalH + 255) / 256;
  int nb = (N + 255) / 256;

  size_t PS8  = (size_t)NpadZ * 8;          // bytes per A8 plane
  size_t PSHe = (size_t)Npad * 8;           // SHORTS per H plane (16 B/node)

  // workspace layout: A8 planes [8][NpadZ][8B] (zero row at idx Npad), H planes [8][Npad][8 shorts]
  char* ws = (char*)d_ws;
  unsigned char*  A8  = (unsigned char*)ws;             // 8*PS8
  unsigned short* H   = (unsigned short*)(ws + 8 * PS8);
  unsigned short* Wt1 = H + 8 * PSHe;                   // 64*128
  unsigned short* Wt2 = Wt1 + 64 * 128;                 // 64*64
  unsigned short* Wt3 = Wt2 + 64 * 64;                  // 64*64
  float* dinv     = (float*)(Wt3 + 64 * 64);            // N
  int*   offsets  = (int*)(dinv + N);                   // N+1
  int*   histG    = offsets + N + 1;                    // NBLK*NBUCK
  int*   scanned  = histG + totalH;                     // NBLK*NBUCK
  unsigned int* packed = (unsigned int*)(scanned + totalH);  // E
  int*   sorted   = (int*)(packed + E);                 // E
  int*   partials = sorted + E;                         // nb2
  float* pmsum    = (float*)(partials + nb2);           // 1
  float* labelsum = pmsum + 1;                          // NBLK

  float* loss = (float*)d_out;
  float* p    = (float*)d_out + 1;

  int nch64   = (N + 63) / 64;
  int aggGrid = nch64 * 8;                  // plane-major: plane = blockIdx % 8
  int ZR = Npad;                            // per-plane zero-row index

  // ---- atomic-free CSR build (+ Wt transpose, plane zero-rows & label-sum in hist) ----
  hist_kernel<<<NBLK, 256, 0, stream>>>(cols, histG, labels, labelsum,
                                        W1, W2, W3, Wt1, Wt2, Wt3,
                                        A8 + (size_t)Npad * 8, PS8, E, N, NBUCK);
  scan_partials_t<<<nb2, 256, 0, stream>>>(histG, partials, totalH, NBUCK);
  scan_block<<<1, 256, 0, stream>>>(partials, nb2, loss, labelsum, pmsum);
  scan_final_t<<<nb2, 256, 0, stream>>>(histG, partials, scanned, totalH, NBUCK);
  scatter_kernel<<<NBLK, 256, 0, stream>>>(rows, cols, scanned, packed, E, NBUCK);

  // ---- CSR finalize + layer-1 GEMM fused (plane output) ----
  csr_finalize_gemm1<<<NBUCK, 1024, 0, stream>>>(packed, scanned, sorted, offsets, dinv,
                                                 x, Wt1, A8, N, E, NBUCK, PS8);

  // ---- layer 1..3: plane-split aggregate (XCD-affine) + mid GEMMs + head ----
  agg_plane<<<aggGrid, 256, 0, stream>>>(A8, offsets, sorted, dinv, b1, H, N, ZR, PS8, PSHe);
  gemm_mid<<<nch64, 256, 0, stream>>>(H, Wt2, dinv, A8, N, PSHe, PS8);
  agg_plane<<<aggGrid, 256, 0, stream>>>(A8, offsets, sorted, dinv, b2, H, N, ZR, PS8, PSHe);
  gemm_mid<<<nch64, 256, 0, stream>>>(H, Wt3, dinv, A8, N, PSHe, PS8);
  agg_plane<<<aggGrid, 256, 0, stream>>>(A8, offsets, sorted, dinv, b3, H, N, ZR, PS8, PSHe);
  head_loss_kernel<<<nb, 256, 0, stream>>>(H, lW1, lb1, lW2, lb2, labels, pmsum, p, loss, N, PSHe);
}

// Round 12
// 305.413 us; speedup vs baseline: 1.2982x; 1.2982x over previous
//
#include <hip/hip_runtime.h>
#include <cstdint>
#include <cstddef>

typedef __attribute__((ext_vector_type(8))) short short8;
typedef __attribute__((ext_vector_type(4))) float f32x4;
typedef __attribute__((ext_vector_type(2))) float f32x2;
typedef __attribute__((ext_vector_type(4))) unsigned int u32x4;

#define NBLK 512        // edge-chunk blocks for hist/scatter (pow2, = 8 XCDs * 64)
#define NBLK_SHIFT 9

__device__ inline int chunk_of_block(int bid) { return ((bid & 7) << 6) | (bid >> 3); }

__device__ inline unsigned short f2bf(float f) {
  union { float f; unsigned int u; } x; x.f = f;
  unsigned int r = x.u + 0x7FFFu + ((x.u >> 16) & 1u);  // round-to-nearest-even
  return (unsigned short)(r >> 16);
}
__device__ inline float bf2f(unsigned short s) {
  union { unsigned int u; float f; } x; x.u = ((unsigned int)s) << 16;
  return x.f;
}

// ---------------- P1: per-block bucket histogram (LDS atomics only) ----------------
// blocks 0..2 transpose W1..W3; block 3 zeroes the gather zero-rows of A8a/A8b.

__global__ __launch_bounds__(256) void hist_kernel(const int* __restrict__ cols,
                                                   int* __restrict__ histG,
                                                   const int* __restrict__ labels,
                                                   float* __restrict__ labelsum,
                                                   const float* __restrict__ W1,
                                                   const float* __restrict__ W2,
                                                   const float* __restrict__ W3,
                                                   unsigned short* __restrict__ Wt1,
                                                   unsigned short* __restrict__ Wt2,
                                                   unsigned short* __restrict__ Wt3,
                                                   unsigned char* __restrict__ zrow_a,
                                                   unsigned char* __restrict__ zrow_b,
                                                   int E, int N, int NBUCK) {
  __shared__ int h[512];
  if (blockIdx.x < 3) {
    const float* W; unsigned short* Wt; int K;
    if (blockIdx.x == 0)      { W = W1; Wt = Wt1; K = 128; }
    else if (blockIdx.x == 1) { W = W2; Wt = Wt2; K = 64; }
    else                      { W = W3; Wt = Wt3; K = 64; }
    int total = K * 64;
    for (int i = threadIdx.x; i < total; i += 256) {
      int n = i / K, k = i - n * K;  // Wt[n][k] = W[k][n]
      Wt[i] = f2bf(W[k * 64 + n]);
    }
  } else if (blockIdx.x == 3 && threadIdx.x < 32) {
    if (threadIdx.x < 16) ((unsigned int*)zrow_a)[threadIdx.x] = 0u;
    else                  ((unsigned int*)zrow_b)[threadIdx.x - 16] = 0u;
  }
  {
    int chunkL = (N + NBLK - 1) / NBLK;
    int ls = blockIdx.x * chunkL;
    int le = min(N, ls + chunkL);
    float v = 0.f;
    for (int i = ls + threadIdx.x; i < le; i += 256) v += (float)labels[i];
#pragma unroll
    for (int o = 32; o > 0; o >>= 1) v += __shfl_down(v, o);
    __shared__ float sl[4];
    if ((threadIdx.x & 63) == 0) sl[threadIdx.x >> 6] = v;
    __syncthreads();
    if (threadIdx.x == 0) labelsum[blockIdx.x] = sl[0] + sl[1] + sl[2] + sl[3];
  }
  for (int i = threadIdx.x; i < NBUCK; i += 256) h[i] = 0;
  __syncthreads();
  int cchunk = chunk_of_block(blockIdx.x);
  int chunk = (E + NBLK - 1) / NBLK;
  int s = cchunk * chunk;
  int e = min(E, s + chunk);
  for (int i = s + threadIdx.x; i < e; i += 256) atomicAdd(&h[cols[i] >> 8], 1);
  __syncthreads();
  for (int i = threadIdx.x; i < NBUCK; i += 256)
    histG[cchunk * NBUCK + i] = h[i];
}

// ---------------- P2: scan of NBUCK*NBLK counts, bucket-major logical order ----------------

__global__ __launch_bounds__(256) void scan_partials_t(const int* __restrict__ histG,
                                                       int* __restrict__ partials,
                                                       int total, int NBUCK) {
  int i = blockIdx.x * 256 + threadIdx.x;
  int v = 0;
  if (i < total) {
    int bucket = i >> NBLK_SHIFT, blk = i & (NBLK - 1);
    v = histG[blk * NBUCK + bucket];
  }
#pragma unroll
  for (int o = 32; o > 0; o >>= 1) v += __shfl_down(v, o);
  __shared__ int s[4];
  if ((threadIdx.x & 63) == 0) s[threadIdx.x >> 6] = v;
  __syncthreads();
  if (threadIdx.x == 0) partials[blockIdx.x] = s[0] + s[1] + s[2] + s[3];
}

__global__ __launch_bounds__(256) void scan_block(int* __restrict__ partials, int nb,
                                                  float* __restrict__ loss,
                                                  const float* __restrict__ labelsum,
                                                  float* __restrict__ pmsum) {
  __shared__ int tmp[256];
  __shared__ int carry;
  int tid = threadIdx.x;
  {
    float v = 0.f;
    for (int i = tid; i < NBLK; i += 256) v += labelsum[i];
#pragma unroll
    for (int o = 32; o > 0; o >>= 1) v += __shfl_down(v, o);
    __shared__ float sl[4];
    if ((tid & 63) == 0) sl[tid >> 6] = v;
    __syncthreads();
    if (tid == 0) *pmsum = sl[0] + sl[1] + sl[2] + sl[3];
  }
  if (tid == 0) { carry = 0; *loss = 0.f; }
  __syncthreads();
  for (int base = 0; base < nb; base += 256) {
    int i = base + tid;
    int v = (i < nb) ? partials[i] : 0;
    tmp[tid] = v;
    __syncthreads();
    int incl = v;
    for (int o = 1; o < 256; o <<= 1) {
      int t = (tid >= o) ? tmp[tid - o] : 0;
      __syncthreads();
      incl += t;
      tmp[tid] = incl;
      __syncthreads();
    }
    int total = tmp[255];
    int c = carry;
    if (i < nb) partials[i] = c + incl - v;  // exclusive
    __syncthreads();
    if (tid == 0) carry = c + total;
    __syncthreads();
  }
}

__global__ __launch_bounds__(256) void scan_final_t(const int* __restrict__ histG,
                                                    const int* __restrict__ partials,
                                                    int* __restrict__ scannedG,
                                                    int total, int NBUCK) {
  __shared__ int tmp[256];
  int tid = threadIdx.x;
  int i = blockIdx.x * 256 + tid;
  int bucket = i >> NBLK_SHIFT, blk = i & (NBLK - 1);
  int v = (i < total) ? histG[blk * NBUCK + bucket] : 0;
  tmp[tid] = v;
  __syncthreads();
  int incl = v;
  for (int o = 1; o < 256; o <<= 1) {
    int t = (tid >= o) ? tmp[tid - o] : 0;
    __syncthreads();
    incl += t;
    tmp[tid] = incl;
    __syncthreads();
  }
  if (i < total) scannedG[blk * NBUCK + bucket] = partials[blockIdx.x] + incl - v;
}

// ---------------- P3: bucket-partition scatter (LDS cursors, no global atomics) ----------------

__global__ __launch_bounds__(256) void scatter_kernel(const int* __restrict__ rows,
                                                      const int* __restrict__ cols,
                                                      const int* __restrict__ scannedG,
                                                      unsigned int* __restrict__ packed,
                                                      int E, int NBUCK) {
  __shared__ int cur[512];
  int cchunk = chunk_of_block(blockIdx.x);
  for (int i = threadIdx.x; i < NBUCK; i += 256)
    cur[i] = scannedG[cchunk * NBUCK + i];
  __syncthreads();
  int chunk = (E + NBLK - 1) / NBLK;
  int s = cchunk * chunk;
  int e = min(E, s + chunk);
  for (int i = s + threadIdx.x; i < e; i += 256) {
    int c = cols[i];
    int r = rows[i];
    int pos = atomicAdd(&cur[c >> 8], 1);
    packed[pos] = ((unsigned int)(c & 255) << 24) | (unsigned int)r;
  }
}

// ---------------- P4: per-bucket CSR finalize + FUSED layer-1 GEMM ----------------

__global__ __launch_bounds__(1024) void csr_finalize_gemm1(const unsigned int* __restrict__ packed,
                                                           const int* __restrict__ scannedG,
                                                           int* __restrict__ sorted_src,
                                                           int* __restrict__ offsets,
                                                           float* __restrict__ dinv,
                                                           const float* __restrict__ xv,
                                                           const unsigned short* __restrict__ Wt,
                                                           unsigned char* __restrict__ out,
                                                           int N, int E, int NBUCK) {
  __shared__ int h[256];
  __shared__ int tmp[256];
  __shared__ int cur[256];
  __shared__ float sdinv[256];
  __shared__ unsigned short gtile[16][16 * 68];   // 34.8 KB gemm staging
  int b = blockIdx.x;
  int tid = threadIdx.x;
  int base = scannedG[b];
  int end = (b + 1 < NBUCK) ? scannedG[b + 1] : E;
  if (tid < 256) h[tid] = 0;
  __syncthreads();
  for (int i = base + tid; i < end; i += 1024)
    atomicAdd(&h[packed[i] >> 24], 1);
  __syncthreads();
  if (tid < 256) {
    int v = h[tid];
    tmp[tid] = v;
  }
  __syncthreads();
  if (tid < 256) {
    int v = h[tid];
    int incl = v;
    for (int o = 1; o < 256; o <<= 1) {
      int t = (tid >= o) ? tmp[tid - o] : 0;
      __syncthreads();
      incl += t;
      tmp[tid] = incl;
      __syncthreads();
    }
    int excl = incl - v;
    int node = b * 256 + tid;
    float dv = rsqrtf((float)(v + 1));  // +1 self loop
    if (node < N) {
      offsets[node] = base + excl;
      dinv[node] = dv;
    }
    sdinv[tid] = dv;
    cur[tid] = base + excl;
    if (b == NBUCK - 1 && tid == 0) offsets[N] = E;
  } else {
    for (int o = 1; o < 256; o <<= 1) { __syncthreads(); __syncthreads(); }
  }
  __syncthreads();
  for (int i = base + tid; i < end; i += 1024) {
    unsigned int p = packed[i];
    int pos = atomicAdd(&cur[p >> 24], 1);
    sorted_src[pos] = (int)(p & 0xFFFFFFu);
  }
  // ---- fused layer-1 GEMM for this bucket's 256 nodes ----
  {
    const int K = 128;
    int wv = tid >> 6;                 // wave 0..15
    int lane = tid & 63;
    int m = lane & 15, quad = lane >> 4;
    int lrow0 = wv * 16;               // local row base in bucket (0..240)
    int m0 = b * 256 + lrow0;
    int rowA = m0 + m;
    bool rowOK = rowA < N;
    f32x4 acc[4] = {{0.f,0.f,0.f,0.f},{0.f,0.f,0.f,0.f},{0.f,0.f,0.f,0.f},{0.f,0.f,0.f,0.f}};
#pragma unroll
    for (int kc = 0; kc < K / 32; ++kc) {
      short8 a = {0, 0, 0, 0, 0, 0, 0, 0};
      if (rowOK) {
        const float* hp = xv + (size_t)rowA * K + kc * 32 + quad * 8;
        float4 p0 = ((const float4*)hp)[0];
        float4 p1 = ((const float4*)hp)[1];
        a[0] = (short)f2bf(p0.x); a[1] = (short)f2bf(p0.y);
        a[2] = (short)f2bf(p0.z); a[3] = (short)f2bf(p0.w);
        a[4] = (short)f2bf(p1.x); a[5] = (short)f2bf(p1.y);
        a[6] = (short)f2bf(p1.z); a[7] = (short)f2bf(p1.w);
      }
#pragma unroll
      for (int t = 0; t < 4; ++t) {
        short8 bb = *(const short8*)(Wt + (size_t)(t * 16 + m) * K + kc * 32 + quad * 8);
        acc[t] = __builtin_amdgcn_mfma_f32_16x16x32_bf16(a, bb, acc[t], 0, 0, 0);
      }
    }
    unsigned short* tw = gtile[wv];
#pragma unroll
    for (int r = 0; r < 4; ++r) {
      int row = quad * 4 + r;
      float dv = sdinv[lrow0 + row];
#pragma unroll
      for (int t = 0; t < 4; ++t)
        tw[row * 68 + t * 16 + m] = f2bf(acc[t][r] * dv);
    }
#pragma unroll
    for (int p = 0; p < 4; ++p) {
      int row = p * 4 + (lane >> 4);
      int ch = lane & 15;  // 4-feature chunk
      int gr = m0 + row;
      if (gr < N) {
        uint2 v = *(const uint2*)(tw + row * 68 + ch * 4);
        float f0 = bf2f((unsigned short)(v.x & 0xFFFFu));
        float f1 = bf2f((unsigned short)(v.x >> 16));
        float f2 = bf2f((unsigned short)(v.y & 0xFFFFu));
        float f3 = bf2f((unsigned short)(v.y >> 16));
        int pk = 0;
        pk = __builtin_amdgcn_cvt_pk_fp8_f32(f0, f1, pk, false);
        pk = __builtin_amdgcn_cvt_pk_fp8_f32(f2, f3, pk, true);
        *(unsigned int*)(out + (size_t)gr * 64 + ch * 4) = (unsigned int)pk;
      }
    }
  }
}

// ---------------- gather core: one node per 4-lane quad, 16B/lane, BRANCHLESS + PINNED ----------
// All 16 u32x4 gathers issue before any convert (sched_barrier). NT flag on the
// gathers: ~0.5% L1 hit odds make L1 allocation pure overhead on the miss path.
// (u32x4 is a clang ext_vector -- __builtin_nontemporal_load rejects HIP's uint4 class.)

#define GATHER_CORE(A8in, ZR)                                                    \
  f32x2 a0={0.f,0.f},a1={0.f,0.f},a2={0.f,0.f},a3={0.f,0.f};                     \
  f32x2 a4={0.f,0.f},a5={0.f,0.f},a6={0.f,0.f},a7={0.f,0.f};                     \
  for (int base = s; base < e; base += 16) {                                     \
    int i0 = base + l4 * 4;                                                      \
    int r0 = (i0     < e) ? __builtin_nontemporal_load(sorted_src + i0)     : ZR;\
    int r1 = (i0 + 1 < e) ? __builtin_nontemporal_load(sorted_src + i0 + 1) : ZR;\
    int r2 = (i0 + 2 < e) ? __builtin_nontemporal_load(sorted_src + i0 + 2) : ZR;\
    int r3 = (i0 + 3 < e) ? __builtin_nontemporal_load(sorted_src + i0 + 3) : ZR;\
    int rj[16];                                                                  \
    _Pragma("unroll")                                                            \
    for (int s4 = 0; s4 < 4; ++s4) {                                             \
      rj[s4 * 4 + 0] = __shfl(r0, qbase + s4);                                   \
      rj[s4 * 4 + 1] = __shfl(r1, qbase + s4);                                   \
      rj[s4 * 4 + 2] = __shfl(r2, qbase + s4);                                   \
      rj[s4 * 4 + 3] = __shfl(r3, qbase + s4);                                   \
    }                                                                            \
    u32x4 v[16];                                                                 \
    _Pragma("unroll")                                                            \
    for (int t = 0; t < 16; ++t)                                                 \
      v[t] = __builtin_nontemporal_load(                                         \
          (const u32x4*)(A8in + ((size_t)(unsigned int)rj[t] << 6) + l4 * 16));  \
    __builtin_amdgcn_sched_barrier(0);                                           \
    _Pragma("unroll")                                                            \
    for (int t = 0; t < 16; ++t) {                                               \
      a0 += __builtin_amdgcn_cvt_pk_f32_fp8((int)v[t][0], false);                \
      a1 += __builtin_amdgcn_cvt_pk_f32_fp8((int)v[t][0], true);                 \
      a2 += __builtin_amdgcn_cvt_pk_f32_fp8((int)v[t][1], false);                \
      a3 += __builtin_amdgcn_cvt_pk_f32_fp8((int)v[t][1], true);                 \
      a4 += __builtin_amdgcn_cvt_pk_f32_fp8((int)v[t][2], false);                \
      a5 += __builtin_amdgcn_cvt_pk_f32_fp8((int)v[t][2], true);                 \
      a6 += __builtin_amdgcn_cvt_pk_f32_fp8((int)v[t][3], false);                \
      a7 += __builtin_amdgcn_cvt_pk_f32_fp8((int)v[t][3], true);                 \
    }                                                                            \
  }

// ---------------- FUSED: gather-aggregate + bias + ReLU + (h @ Wnext)*dinv -> A8out ----------------

__global__ __launch_bounds__(256, 4) void agg_gemm(const unsigned char* __restrict__ A8in,
                                                   const int* __restrict__ offsets,
                                                   const int* __restrict__ sorted_src,
                                                   const float* __restrict__ dinv,
                                                   const float* __restrict__ bias,
                                                   const unsigned short* __restrict__ Wt,
                                                   unsigned char* __restrict__ A8out,
                                                   int N, int ZR) {
  __shared__ unsigned short hl[64 * 72];
  int lane = threadIdx.x & 63;
  int cl = threadIdx.x >> 2;             // local node 0..63
  int c = blockIdx.x * 64 + cl;
  int l4 = lane & 3;                     // 16B chunk of the 64B row
  int qbase = lane & 60;
  bool ok = c < N;
  int s = 0, e = 0;
  float dc = 0.f;
  uint2 svr0 = {0u, 0u}, svr1 = {0u, 0u};
  if (ok) {
    s = offsets[c]; e = offsets[c + 1];
    dc = dinv[c];
    svr0 = *(const uint2*)(A8in + ((size_t)c << 6) + l4 * 16);
    svr1 = *(const uint2*)(A8in + ((size_t)c << 6) + l4 * 16 + 8);
  }
  GATHER_CORE(A8in, ZR)
  {
    short8 w0 = {0,0,0,0,0,0,0,0}, w1 = {0,0,0,0,0,0,0,0};
    if (ok) {
      a0 += __builtin_amdgcn_cvt_pk_f32_fp8((int)svr0.x, false);
      a1 += __builtin_amdgcn_cvt_pk_f32_fp8((int)svr0.x, true);
      a2 += __builtin_amdgcn_cvt_pk_f32_fp8((int)svr0.y, false);
      a3 += __builtin_amdgcn_cvt_pk_f32_fp8((int)svr0.y, true);
      a4 += __builtin_amdgcn_cvt_pk_f32_fp8((int)svr1.x, false);
      a5 += __builtin_amdgcn_cvt_pk_f32_fp8((int)svr1.x, true);
      a6 += __builtin_amdgcn_cvt_pk_f32_fp8((int)svr1.y, false);
      a7 += __builtin_amdgcn_cvt_pk_f32_fp8((int)svr1.y, true);
      float accf[16] = {a0[0],a0[1],a1[0],a1[1],a2[0],a2[1],a3[0],a3[1],
                        a4[0],a4[1],a5[0],a5[1],a6[0],a6[1],a7[0],a7[1]};
      const float* bp = bias + l4 * 16;
#pragma unroll
      for (int q = 0; q < 8; ++q) {
        float v = fmaf(accf[q], dc, bp[q]);
        w0[q] = (short)f2bf(v > 0.f ? v : 0.f);
      }
#pragma unroll
      for (int q = 0; q < 8; ++q) {
        float v = fmaf(accf[8 + q], dc, bp[8 + q]);
        w1[q] = (short)f2bf(v > 0.f ? v : 0.f);
      }
    }
    short8* dst = (short8*)(hl + cl * 72 + l4 * 16);
    dst[0] = w0; dst[1] = w1;
  }
  __syncthreads();
  int wv = threadIdx.x >> 6;
  int m = lane & 15, quad = lane >> 4;
  int rbase = wv * 16;
  f32x4 acc2[4] = {{0.f,0.f,0.f,0.f},{0.f,0.f,0.f,0.f},{0.f,0.f,0.f,0.f},{0.f,0.f,0.f,0.f}};
#pragma unroll
  for (int kc = 0; kc < 2; ++kc) {
    short8 a = *(const short8*)(hl + (rbase + m) * 72 + kc * 32 + quad * 8);
#pragma unroll
    for (int t = 0; t < 4; ++t) {
      short8 b = *(const short8*)(Wt + (size_t)(t * 16 + m) * 64 + kc * 32 + quad * 8);
      acc2[t] = __builtin_amdgcn_mfma_f32_16x16x32_bf16(a, b, acc2[t], 0, 0, 0);
    }
  }
  __syncthreads();
#pragma unroll
  for (int r = 0; r < 4; ++r) {
    int row = rbase + quad * 4 + r;
    int gr = blockIdx.x * 64 + row;
    float dv = dinv[gr < N ? gr : 0];
#pragma unroll
    for (int t = 0; t < 4; ++t)
      hl[row * 72 + t * 16 + m] = f2bf(acc2[t][r] * dv);
  }
  __syncthreads();
#pragma unroll
  for (int u = 0; u < 4; ++u) {
    int id = u * 256 + threadIdx.x;
    int row = id >> 4, ch = id & 15;
    int gr = blockIdx.x * 64 + row;
    if (gr < N) {
      uint2 v = *(const uint2*)(hl + row * 72 + ch * 4);
      float f0 = bf2f((unsigned short)(v.x & 0xFFFFu));
      float f1 = bf2f((unsigned short)(v.x >> 16));
      float f2 = bf2f((unsigned short)(v.y & 0xFFFFu));
      float f3 = bf2f((unsigned short)(v.y >> 16));
      int pk = 0;
      pk = __builtin_amdgcn_cvt_pk_fp8_f32(f0, f1, pk, false);
      pk = __builtin_amdgcn_cvt_pk_fp8_f32(f2, f3, pk, true);
      *(unsigned int*)(A8out + (size_t)gr * 64 + ch * 4) = (unsigned int)pk;
    }
  }
}

// ---------------- FUSED: gather-aggregate (layer 3) + MLP head + sigmoid + BCE ----------------

__global__ __launch_bounds__(256, 4) void agg_head(const unsigned char* __restrict__ A8in,
                                                   const int* __restrict__ offsets,
                                                   const int* __restrict__ sorted_src,
                                                   const float* __restrict__ dinv,
                                                   const float* __restrict__ bias,
                                                   const float* __restrict__ lW1,
                                                   const float* __restrict__ lb1,
                                                   const float* __restrict__ lW2,
                                                   const float* __restrict__ lb2,
                                                   const int* __restrict__ labels,
                                                   const float* __restrict__ pmsum,
                                                   float* __restrict__ p,
                                                   float* __restrict__ loss,
                                                   int N, int ZR) {
  int lane = threadIdx.x & 63;
  int cl = threadIdx.x >> 2;
  int c = blockIdx.x * 64 + cl;
  int l4 = lane & 3;
  int qbase = lane & 60;
  bool ok = c < N;
  int s = 0, e = 0;
  float dc = 0.f;
  uint2 svr0 = {0u, 0u}, svr1 = {0u, 0u};
  if (ok) {
    s = offsets[c]; e = offsets[c + 1];
    dc = dinv[c];
    svr0 = *(const uint2*)(A8in + ((size_t)c << 6) + l4 * 16);
    svr1 = *(const uint2*)(A8in + ((size_t)c << 6) + l4 * 16 + 8);
  }
  GATHER_CORE(A8in, ZR)
  float contrib = 0.f;
  {
    a0 += __builtin_amdgcn_cvt_pk_f32_fp8((int)svr0.x, false);
    a1 += __builtin_amdgcn_cvt_pk_f32_fp8((int)svr0.x, true);
    a2 += __builtin_amdgcn_cvt_pk_f32_fp8((int)svr0.y, false);
    a3 += __builtin_amdgcn_cvt_pk_f32_fp8((int)svr0.y, true);
    a4 += __builtin_amdgcn_cvt_pk_f32_fp8((int)svr1.x, false);
    a5 += __builtin_amdgcn_cvt_pk_f32_fp8((int)svr1.x, true);
    a6 += __builtin_amdgcn_cvt_pk_f32_fp8((int)svr1.y, false);
    a7 += __builtin_amdgcn_cvt_pk_f32_fp8((int)svr1.y, true);
    float accf[16] = {a0[0],a0[1],a1[0],a1[1],a2[0],a2[1],a3[0],a3[1],
                      a4[0],a4[1],a5[0],a5[1],a6[0],a6[1],a7[0],a7[1]};
    const float* bp = bias + l4 * 16;
    float hq[16];
#pragma unroll
    for (int q = 0; q < 16; ++q) {
      float v = fmaf(accf[q], dc, bp[q]);
      hq[q] = v > 0.f ? v : 0.f;
    }
    float acc8[8] = {0.f,0.f,0.f,0.f,0.f,0.f,0.f,0.f};
#pragma unroll
    for (int q = 0; q < 16; ++q) {
      int k = l4 * 16 + q;
#pragma unroll
      for (int j = 0; j < 8; ++j) acc8[j] = fmaf(hq[q], lW1[k * 8 + j], acc8[j]);
    }
#pragma unroll
    for (int j = 0; j < 8; ++j) {
      acc8[j] += __shfl_xor(acc8[j], 1);
      acc8[j] += __shfl_xor(acc8[j], 2);
    }
    if (ok && l4 == 0) {
      float sv = lb2[0];
#pragma unroll
      for (int j = 0; j < 8; ++j) {
        float a = acc8[j] + lb1[j];
        a = a > 0.f ? a : 0.f;
        sv = fmaf(a, lW2[j], sv);
      }
      float pv = 1.0f / (1.0f + expf(-sv));
      p[c] = pv;
      float pm = *pmsum / (float)N;
      float y = (float)labels[c];
      float w = y * (1.f - pm) + (1.f - y) * pm;
      float pc = fminf(fmaxf(pv, 1e-7f), 1.f - 1e-7f);
      float bce = -(y * logf(pc) + (1.f - y) * logf(1.f - pc));
      contrib = w * bce / (float)N;
    }
  }
#pragma unroll
  for (int o = 32; o > 0; o >>= 1) contrib += __shfl_down(contrib, o);
  __shared__ float sh[4];
  int wv = threadIdx.x >> 6;
  if (lane == 0) sh[wv] = contrib;
  __syncthreads();
  if (threadIdx.x == 0) atomicAdd(loss, sh[0] + sh[1] + sh[2] + sh[3]);
}

// ---------------- launch ----------------

extern "C" void kernel_launch(void* const* d_in, const int* in_sizes, int n_in,
                              void* d_out, int out_size, void* d_ws, size_t ws_size,
                              hipStream_t stream) {
  const float* x      = (const float*)d_in[0];
  const int*   ei     = (const int*)d_in[1];
  const int*   labels = (const int*)d_in[2];
  const float* W1 = (const float*)d_in[3];
  const float* b1 = (const float*)d_in[4];
  const float* W2 = (const float*)d_in[5];
  const float* b2 = (const float*)d_in[6];
  const float* W3 = (const float*)d_in[7];
  const float* b3 = (const float*)d_in[8];
  const float* lW1 = (const float*)d_in[9];
  const float* lb1 = (const float*)d_in[10];
  const float* lW2 = (const float*)d_in[11];
  const float* lb2 = (const float*)d_in[12];

  int N = in_sizes[2];            // labels: [N,1]
  int E = in_sizes[1] / 2;        // edge_index: [2,E]
  const int* rows = ei;           // sources
  const int* cols = ei + E;       // targets (aggregation)

  int Npad = (N + 63) & ~63;
  int NBUCK = (N + 255) >> 8;               // 256-node buckets
  int totalH = NBUCK * NBLK;                // histogram entries
  int nb2 = (totalH + 255) / 256;

  // workspace layout: A8 buffers have one extra zero-row at index Npad (gather clamp)
  size_t a8stride = (size_t)Npad * 64 + 256;
  char* ws = (char*)d_ws;
  unsigned char*  A8a = (unsigned char*)ws;
  unsigned char*  A8b = (unsigned char*)(ws + a8stride);
  unsigned short* Wt1 = (unsigned short*)(ws + (size_t)Npad * 192); // 64*128
  unsigned short* Wt2 = Wt1 + 64 * 128;                 // 64*64
  unsigned short* Wt3 = Wt2 + 64 * 64;                  // 64*64
  float* dinv     = (float*)(Wt3 + 64 * 64);            // N
  int*   offsets  = (int*)(dinv + N);                   // N+1
  int*   histG    = offsets + N + 1;                    // NBLK*NBUCK
  int*   scanned  = histG + totalH;                     // NBLK*NBUCK
  unsigned int* packed = (unsigned int*)(scanned + totalH);  // E
  int*   sorted   = (int*)(packed + E);                 // E
  int*   partials = sorted + E;                         // nb2
  float* pmsum    = (float*)(partials + nb2);           // 1
  float* labelsum = pmsum + 1;                          // NBLK

  float* loss = (float*)d_out;
  float* p    = (float*)d_out + 1;

  int aggBlocks  = (N + 63) / 64;
  int ZR = Npad;                   // zero-row index

  // ---- atomic-free CSR build (+ Wt transpose, zero-rows & label-sum folded into hist) ----
  hist_kernel<<<NBLK, 256, 0, stream>>>(cols, histG, labels, labelsum,
                                        W1, W2, W3, Wt1, Wt2, Wt3,
                                        A8a + (size_t)Npad * 64, A8b + (size_t)Npad * 64,
                                        E, N, NBUCK);
  scan_partials_t<<<nb2, 256, 0, stream>>>(histG, partials, totalH, NBUCK);
  scan_block<<<1, 256, 0, stream>>>(partials, nb2, loss, labelsum, pmsum);
  scan_final_t<<<nb2, 256, 0, stream>>>(histG, partials, scanned, totalH, NBUCK);
  scatter_kernel<<<NBLK, 256, 0, stream>>>(rows, cols, scanned, packed, E, NBUCK);

  // ---- CSR finalize + layer-1 GEMM fused (dinv is bucket-local) ----
  csr_finalize_gemm1<<<NBUCK, 1024, 0, stream>>>(packed, scanned, sorted, offsets, dinv,
                                                 x, Wt1, A8a, N, E, NBUCK);

  // ---- fused layers: agg1+gemm2, agg2+gemm3, agg3+head ----
  agg_gemm<<<aggBlocks, 256, 0, stream>>>(A8a, offsets, sorted, dinv, b1, Wt2, A8b, N, ZR);
  agg_gemm<<<aggBlocks, 256, 0, stream>>>(A8b, offsets, sorted, dinv, b2, Wt3, A8a, N, ZR);
  agg_head<<<aggBlocks, 256, 0, stream>>>(A8a, offsets, sorted, dinv, b3,
                                          lW1, lb1, lW2, lb2, labels, pmsum, p, loss, N, ZR);
}

// Round 13
// 280.701 us; speedup vs baseline: 1.4125x; 1.0880x over previous
//
#include <hip/hip_runtime.h>
#include <cstdint>
#include <cstddef>

typedef __attribute__((ext_vector_type(8))) short short8;
typedef __attribute__((ext_vector_type(4))) float f32x4;
typedef __attribute__((ext_vector_type(2))) float f32x2;

#define NBLK 512        // edge-chunk blocks for hist/scatter (pow2, = 8 XCDs * 64)
#define NBLK_SHIFT 9

__device__ inline int chunk_of_block(int bid) { return ((bid & 7) << 6) | (bid >> 3); }

__device__ inline unsigned short f2bf(float f) {
  union { float f; unsigned int u; } x; x.f = f;
  unsigned int r = x.u + 0x7FFFu + ((x.u >> 16) & 1u);  // round-to-nearest-even
  return (unsigned short)(r >> 16);
}
__device__ inline float bf2f(unsigned short s) {
  union { unsigned int u; float f; } x; x.u = ((unsigned int)s) << 16;
  return x.f;
}

// ---------------- P1: per-block bucket histogram (LDS atomics only) ----------------
// blocks 0..2 transpose W1..W3; block 3 zeroes the gather zero-rows of A8a/A8b.

__global__ __launch_bounds__(256) void hist_kernel(const int* __restrict__ cols,
                                                   int* __restrict__ histG,
                                                   const int* __restrict__ labels,
                                                   float* __restrict__ labelsum,
                                                   const float* __restrict__ W1,
                                                   const float* __restrict__ W2,
                                                   const float* __restrict__ W3,
                                                   unsigned short* __restrict__ Wt1,
                                                   unsigned short* __restrict__ Wt2,
                                                   unsigned short* __restrict__ Wt3,
                                                   unsigned char* __restrict__ zrow_a,
                                                   unsigned char* __restrict__ zrow_b,
                                                   int E, int N, int NBUCK) {
  __shared__ int h[512];
  if (blockIdx.x < 3) {
    const float* W; unsigned short* Wt; int K;
    if (blockIdx.x == 0)      { W = W1; Wt = Wt1; K = 128; }
    else if (blockIdx.x == 1) { W = W2; Wt = Wt2; K = 64; }
    else                      { W = W3; Wt = Wt3; K = 64; }
    int total = K * 64;
    for (int i = threadIdx.x; i < total; i += 256) {
      int n = i / K, k = i - n * K;  // Wt[n][k] = W[k][n]
      Wt[i] = f2bf(W[k * 64 + n]);
    }
  } else if (blockIdx.x == 3 && threadIdx.x < 32) {
    if (threadIdx.x < 16) ((unsigned int*)zrow_a)[threadIdx.x] = 0u;
    else                  ((unsigned int*)zrow_b)[threadIdx.x - 16] = 0u;
  }
  {
    int chunkL = (N + NBLK - 1) / NBLK;
    int ls = blockIdx.x * chunkL;
    int le = min(N, ls + chunkL);
    float v = 0.f;
    for (int i = ls + threadIdx.x; i < le; i += 256) v += (float)labels[i];
#pragma unroll
    for (int o = 32; o > 0; o >>= 1) v += __shfl_down(v, o);
    __shared__ float sl[4];
    if ((threadIdx.x & 63) == 0) sl[threadIdx.x >> 6] = v;
    __syncthreads();
    if (threadIdx.x == 0) labelsum[blockIdx.x] = sl[0] + sl[1] + sl[2] + sl[3];
  }
  for (int i = threadIdx.x; i < NBUCK; i += 256) h[i] = 0;
  __syncthreads();
  int cchunk = chunk_of_block(blockIdx.x);
  int chunk = (E + NBLK - 1) / NBLK;
  int s = cchunk * chunk;
  int e = min(E, s + chunk);
  for (int i = s + threadIdx.x; i < e; i += 256) atomicAdd(&h[cols[i] >> 8], 1);
  __syncthreads();
  for (int i = threadIdx.x; i < NBUCK; i += 256)
    histG[cchunk * NBUCK + i] = h[i];
}

// ---------------- P2: scan of NBUCK*NBLK counts, bucket-major logical order ----------------

__global__ __launch_bounds__(256) void scan_partials_t(const int* __restrict__ histG,
                                                       int* __restrict__ partials,
                                                       int total, int NBUCK) {
  int i = blockIdx.x * 256 + threadIdx.x;
  int v = 0;
  if (i < total) {
    int bucket = i >> NBLK_SHIFT, blk = i & (NBLK - 1);
    v = histG[blk * NBUCK + bucket];
  }
#pragma unroll
  for (int o = 32; o > 0; o >>= 1) v += __shfl_down(v, o);
  __shared__ int s[4];
  if ((threadIdx.x & 63) == 0) s[threadIdx.x >> 6] = v;
  __syncthreads();
  if (threadIdx.x == 0) partials[blockIdx.x] = s[0] + s[1] + s[2] + s[3];
}

__global__ __launch_bounds__(256) void scan_block(int* __restrict__ partials, int nb,
                                                  float* __restrict__ loss,
                                                  const float* __restrict__ labelsum,
                                                  float* __restrict__ pmsum) {
  __shared__ int tmp[256];
  __shared__ int carry;
  int tid = threadIdx.x;
  {
    float v = 0.f;
    for (int i = tid; i < NBLK; i += 256) v += labelsum[i];
#pragma unroll
    for (int o = 32; o > 0; o >>= 1) v += __shfl_down(v, o);
    __shared__ float sl[4];
    if ((tid & 63) == 0) sl[tid >> 6] = v;
    __syncthreads();
    if (tid == 0) *pmsum = sl[0] + sl[1] + sl[2] + sl[3];
  }
  if (tid == 0) { carry = 0; *loss = 0.f; }
  __syncthreads();
  for (int base = 0; base < nb; base += 256) {
    int i = base + tid;
    int v = (i < nb) ? partials[i] : 0;
    tmp[tid] = v;
    __syncthreads();
    int incl = v;
    for (int o = 1; o < 256; o <<= 1) {
      int t = (tid >= o) ? tmp[tid - o] : 0;
      __syncthreads();
      incl += t;
      tmp[tid] = incl;
      __syncthreads();
    }
    int total = tmp[255];
    int c = carry;
    if (i < nb) partials[i] = c + incl - v;  // exclusive
    __syncthreads();
    if (tid == 0) carry = c + total;
    __syncthreads();
  }
}

__global__ __launch_bounds__(256) void scan_final_t(const int* __restrict__ histG,
                                                    const int* __restrict__ partials,
                                                    int* __restrict__ scannedG,
                                                    int total, int NBUCK) {
  __shared__ int tmp[256];
  int tid = threadIdx.x;
  int i = blockIdx.x * 256 + tid;
  int bucket = i >> NBLK_SHIFT, blk = i & (NBLK - 1);
  int v = (i < total) ? histG[blk * NBUCK + bucket] : 0;
  tmp[tid] = v;
  __syncthreads();
  int incl = v;
  for (int o = 1; o < 256; o <<= 1) {
    int t = (tid >= o) ? tmp[tid - o] : 0;
    __syncthreads();
    incl += t;
    tmp[tid] = incl;
    __syncthreads();
  }
  if (i < total) scannedG[blk * NBUCK + bucket] = partials[blockIdx.x] + incl - v;
}

// ---------------- P3: bucket-partition scatter (LDS cursors, no global atomics) ----------------

__global__ __launch_bounds__(256) void scatter_kernel(const int* __restrict__ rows,
                                                      const int* __restrict__ cols,
                                                      const int* __restrict__ scannedG,
                                                      unsigned int* __restrict__ packed,
                                                      int E, int NBUCK) {
  __shared__ int cur[512];
  int cchunk = chunk_of_block(blockIdx.x);
  for (int i = threadIdx.x; i < NBUCK; i += 256)
    cur[i] = scannedG[cchunk * NBUCK + i];
  __syncthreads();
  int chunk = (E + NBLK - 1) / NBLK;
  int s = cchunk * chunk;
  int e = min(E, s + chunk);
  for (int i = s + threadIdx.x; i < e; i += 256) {
    int c = cols[i];
    int r = rows[i];
    int pos = atomicAdd(&cur[c >> 8], 1);
    packed[pos] = ((unsigned int)(c & 255) << 24) | (unsigned int)r;
  }
}

// ---------------- P4: per-bucket CSR finalize + FUSED layer-1 GEMM ----------------

__global__ __launch_bounds__(1024) void csr_finalize_gemm1(const unsigned int* __restrict__ packed,
                                                           const int* __restrict__ scannedG,
                                                           int* __restrict__ sorted_src,
                                                           int* __restrict__ offsets,
                                                           float* __restrict__ dinv,
                                                           const float* __restrict__ xv,
                                                           const unsigned short* __restrict__ Wt,
                                                           unsigned char* __restrict__ out,
                                                           int N, int E, int NBUCK) {
  __shared__ int h[256];
  __shared__ int tmp[256];
  __shared__ int cur[256];
  __shared__ float sdinv[256];
  __shared__ unsigned short gtile[16][16 * 68];   // 34.8 KB gemm staging
  int b = blockIdx.x;
  int tid = threadIdx.x;
  int base = scannedG[b];
  int end = (b + 1 < NBUCK) ? scannedG[b + 1] : E;
  if (tid < 256) h[tid] = 0;
  __syncthreads();
  for (int i = base + tid; i < end; i += 1024)
    atomicAdd(&h[packed[i] >> 24], 1);
  __syncthreads();
  if (tid < 256) {
    int v = h[tid];
    tmp[tid] = v;
  }
  __syncthreads();
  if (tid < 256) {
    int v = h[tid];
    int incl = v;
    for (int o = 1; o < 256; o <<= 1) {
      int t = (tid >= o) ? tmp[tid - o] : 0;
      __syncthreads();
      incl += t;
      tmp[tid] = incl;
      __syncthreads();
    }
    int excl = incl - v;
    int node = b * 256 + tid;
    float dv = rsqrtf((float)(v + 1));  // +1 self loop
    if (node < N) {
      offsets[node] = base + excl;
      dinv[node] = dv;
    }
    sdinv[tid] = dv;
    cur[tid] = base + excl;
    if (b == NBUCK - 1 && tid == 0) offsets[N] = E;
  } else {
    for (int o = 1; o < 256; o <<= 1) { __syncthreads(); __syncthreads(); }
  }
  __syncthreads();
  for (int i = base + tid; i < end; i += 1024) {
    unsigned int p = packed[i];
    int pos = atomicAdd(&cur[p >> 24], 1);
    sorted_src[pos] = (int)(p & 0xFFFFFFu);
  }
  // ---- fused layer-1 GEMM for this bucket's 256 nodes ----
  {
    const int K = 128;
    int wv = tid >> 6;                 // wave 0..15
    int lane = tid & 63;
    int m = lane & 15, quad = lane >> 4;
    int lrow0 = wv * 16;               // local row base in bucket (0..240)
    int m0 = b * 256 + lrow0;
    int rowA = m0 + m;
    bool rowOK = rowA < N;
    f32x4 acc[4] = {{0.f,0.f,0.f,0.f},{0.f,0.f,0.f,0.f},{0.f,0.f,0.f,0.f},{0.f,0.f,0.f,0.f}};
#pragma unroll
    for (int kc = 0; kc < K / 32; ++kc) {
      short8 a = {0, 0, 0, 0, 0, 0, 0, 0};
      if (rowOK) {
        const float* hp = xv + (size_t)rowA * K + kc * 32 + quad * 8;
        float4 p0 = ((const float4*)hp)[0];
        float4 p1 = ((const float4*)hp)[1];
        a[0] = (short)f2bf(p0.x); a[1] = (short)f2bf(p0.y);
        a[2] = (short)f2bf(p0.z); a[3] = (short)f2bf(p0.w);
        a[4] = (short)f2bf(p1.x); a[5] = (short)f2bf(p1.y);
        a[6] = (short)f2bf(p1.z); a[7] = (short)f2bf(p1.w);
      }
#pragma unroll
      for (int t = 0; t < 4; ++t) {
        short8 bb = *(const short8*)(Wt + (size_t)(t * 16 + m) * K + kc * 32 + quad * 8);
        acc[t] = __builtin_amdgcn_mfma_f32_16x16x32_bf16(a, bb, acc[t], 0, 0, 0);
      }
    }
    unsigned short* tw = gtile[wv];
#pragma unroll
    for (int r = 0; r < 4; ++r) {
      int row = quad * 4 + r;
      float dv = sdinv[lrow0 + row];
#pragma unroll
      for (int t = 0; t < 4; ++t)
        tw[row * 68 + t * 16 + m] = f2bf(acc[t][r] * dv);
    }
#pragma unroll
    for (int p = 0; p < 4; ++p) {
      int row = p * 4 + (lane >> 4);
      int ch = lane & 15;  // 4-feature chunk
      int gr = m0 + row;
      if (gr < N) {
        uint2 v = *(const uint2*)(tw + row * 68 + ch * 4);
        float f0 = bf2f((unsigned short)(v.x & 0xFFFFu));
        float f1 = bf2f((unsigned short)(v.x >> 16));
        float f2 = bf2f((unsigned short)(v.y & 0xFFFFu));
        float f3 = bf2f((unsigned short)(v.y >> 16));
        int pk = 0;
        pk = __builtin_amdgcn_cvt_pk_fp8_f32(f0, f1, pk, false);
        pk = __builtin_amdgcn_cvt_pk_fp8_f32(f2, f3, pk, true);
        *(unsigned int*)(out + (size_t)gr * 64 + ch * 4) = (unsigned int)pk;
      }
    }
  }
}

// ---------------- gather core: one node per 4-lane quad, 16B/lane, BRANCHLESS + PINNED ----------
// All 16 uint4 gathers issue before any convert (sched_barrier). Plain loads:
// nt variant measured WORSE (r12: L2 retention dropped, FETCH 51->56 MB).

#define GATHER_CORE(A8in, ZR)                                                    \
  f32x2 a0={0.f,0.f},a1={0.f,0.f},a2={0.f,0.f},a3={0.f,0.f};                     \
  f32x2 a4={0.f,0.f},a5={0.f,0.f},a6={0.f,0.f},a7={0.f,0.f};                     \
  for (int base = s; base < e; base += 16) {                                     \
    int i0 = base + l4 * 4;                                                      \
    int r0 = (i0     < e) ? __builtin_nontemporal_load(sorted_src + i0)     : ZR;\
    int r1 = (i0 + 1 < e) ? __builtin_nontemporal_load(sorted_src + i0 + 1) : ZR;\
    int r2 = (i0 + 2 < e) ? __builtin_nontemporal_load(sorted_src + i0 + 2) : ZR;\
    int r3 = (i0 + 3 < e) ? __builtin_nontemporal_load(sorted_src + i0 + 3) : ZR;\
    int rj[16];                                                                  \
    _Pragma("unroll")                                                            \
    for (int s4 = 0; s4 < 4; ++s4) {                                             \
      rj[s4 * 4 + 0] = __shfl(r0, qbase + s4);                                   \
      rj[s4 * 4 + 1] = __shfl(r1, qbase + s4);                                   \
      rj[s4 * 4 + 2] = __shfl(r2, qbase + s4);                                   \
      rj[s4 * 4 + 3] = __shfl(r3, qbase + s4);                                   \
    }                                                                            \
    uint4 v[16];                                                                 \
    _Pragma("unroll")                                                            \
    for (int t = 0; t < 16; ++t)                                                 \
      v[t] = *(const uint4*)(A8in + ((size_t)(unsigned int)rj[t] << 6) + l4 * 16);\
    __builtin_amdgcn_sched_barrier(0);                                           \
    _Pragma("unroll")                                                            \
    for (int t = 0; t < 16; ++t) {                                               \
      a0 += __builtin_amdgcn_cvt_pk_f32_fp8((int)v[t].x, false);                 \
      a1 += __builtin_amdgcn_cvt_pk_f32_fp8((int)v[t].x, true);                  \
      a2 += __builtin_amdgcn_cvt_pk_f32_fp8((int)v[t].y, false);                 \
      a3 += __builtin_amdgcn_cvt_pk_f32_fp8((int)v[t].y, true);                  \
      a4 += __builtin_amdgcn_cvt_pk_f32_fp8((int)v[t].z, false);                 \
      a5 += __builtin_amdgcn_cvt_pk_f32_fp8((int)v[t].z, true);                  \
      a6 += __builtin_amdgcn_cvt_pk_f32_fp8((int)v[t].w, false);                 \
      a7 += __builtin_amdgcn_cvt_pk_f32_fp8((int)v[t].w, true);                  \
    }                                                                            \
  }

// ---------------- FUSED: gather-aggregate + bias + ReLU + (h @ Wnext)*dinv -> A8out ----------------

__global__ __launch_bounds__(256, 4) void agg_gemm(const unsigned char* __restrict__ A8in,
                                                   const int* __restrict__ offsets,
                                                   const int* __restrict__ sorted_src,
                                                   const float* __restrict__ dinv,
                                                   const float* __restrict__ bias,
                                                   const unsigned short* __restrict__ Wt,
                                                   unsigned char* __restrict__ A8out,
                                                   int N, int ZR) {
  __shared__ unsigned short hl[64 * 72];
  int lane = threadIdx.x & 63;
  int cl = threadIdx.x >> 2;             // local node 0..63
  int c = blockIdx.x * 64 + cl;
  int l4 = lane & 3;                     // 16B chunk of the 64B row
  int qbase = lane & 60;
  bool ok = c < N;
  int s = 0, e = 0;
  float dc = 0.f;
  uint4 svr = {0u, 0u, 0u, 0u};
  if (ok) {
    s = offsets[c]; e = offsets[c + 1];
    dc = dinv[c];
    svr = *(const uint4*)(A8in + ((size_t)c << 6) + l4 * 16);
  }
  GATHER_CORE(A8in, ZR)
  {
    short8 w0 = {0,0,0,0,0,0,0,0}, w1 = {0,0,0,0,0,0,0,0};
    if (ok) {
      a0 += __builtin_amdgcn_cvt_pk_f32_fp8((int)svr.x, false);
      a1 += __builtin_amdgcn_cvt_pk_f32_fp8((int)svr.x, true);
      a2 += __builtin_amdgcn_cvt_pk_f32_fp8((int)svr.y, false);
      a3 += __builtin_amdgcn_cvt_pk_f32_fp8((int)svr.y, true);
      a4 += __builtin_amdgcn_cvt_pk_f32_fp8((int)svr.z, false);
      a5 += __builtin_amdgcn_cvt_pk_f32_fp8((int)svr.z, true);
      a6 += __builtin_amdgcn_cvt_pk_f32_fp8((int)svr.w, false);
      a7 += __builtin_amdgcn_cvt_pk_f32_fp8((int)svr.w, true);
      float accf[16] = {a0[0],a0[1],a1[0],a1[1],a2[0],a2[1],a3[0],a3[1],
                        a4[0],a4[1],a5[0],a5[1],a6[0],a6[1],a7[0],a7[1]};
      const float* bp = bias + l4 * 16;
#pragma unroll
      for (int q = 0; q < 8; ++q) {
        float v = fmaf(accf[q], dc, bp[q]);
        w0[q] = (short)f2bf(v > 0.f ? v : 0.f);
      }
#pragma unroll
      for (int q = 0; q < 8; ++q) {
        float v = fmaf(accf[8 + q], dc, bp[8 + q]);
        w1[q] = (short)f2bf(v > 0.f ? v : 0.f);
      }
    }
    short8* dst = (short8*)(hl + cl * 72 + l4 * 16);
    dst[0] = w0; dst[1] = w1;
  }
  __syncthreads();
  int wv = threadIdx.x >> 6;
  int m = lane & 15, quad = lane >> 4;
  int rbase = wv * 16;
  f32x4 acc2[4] = {{0.f,0.f,0.f,0.f},{0.f,0.f,0.f,0.f},{0.f,0.f,0.f,0.f},{0.f,0.f,0.f,0.f}};
#pragma unroll
  for (int kc = 0; kc < 2; ++kc) {
    short8 a = *(const short8*)(hl + (rbase + m) * 72 + kc * 32 + quad * 8);
#pragma unroll
    for (int t = 0; t < 4; ++t) {
      short8 b = *(const short8*)(Wt + (size_t)(t * 16 + m) * 64 + kc * 32 + quad * 8);
      acc2[t] = __builtin_amdgcn_mfma_f32_16x16x32_bf16(a, b, acc2[t], 0, 0, 0);
    }
  }
  __syncthreads();
#pragma unroll
  for (int r = 0; r < 4; ++r) {
    int row = rbase + quad * 4 + r;
    int gr = blockIdx.x * 64 + row;
    float dv = dinv[gr < N ? gr : 0];
#pragma unroll
    for (int t = 0; t < 4; ++t)
      hl[row * 72 + t * 16 + m] = f2bf(acc2[t][r] * dv);
  }
  __syncthreads();
#pragma unroll
  for (int u = 0; u < 4; ++u) {
    int id = u * 256 + threadIdx.x;
    int row = id >> 4, ch = id & 15;
    int gr = blockIdx.x * 64 + row;
    if (gr < N) {
      uint2 v = *(const uint2*)(hl + row * 72 + ch * 4);
      float f0 = bf2f((unsigned short)(v.x & 0xFFFFu));
      float f1 = bf2f((unsigned short)(v.x >> 16));
      float f2 = bf2f((unsigned short)(v.y & 0xFFFFu));
      float f3 = bf2f((unsigned short)(v.y >> 16));
      int pk = 0;
      pk = __builtin_amdgcn_cvt_pk_fp8_f32(f0, f1, pk, false);
      pk = __builtin_amdgcn_cvt_pk_fp8_f32(f2, f3, pk, true);
      *(unsigned int*)(A8out + (size_t)gr * 64 + ch * 4) = (unsigned int)pk;
    }
  }
}

// ---------------- FUSED: gather-aggregate (layer 3) + MLP head + sigmoid + BCE ----------------

__global__ __launch_bounds__(256, 4) void agg_head(const unsigned char* __restrict__ A8in,
                                                   const int* __restrict__ offsets,
                                                   const int* __restrict__ sorted_src,
                                                   const float* __restrict__ dinv,
                                                   const float* __restrict__ bias,
                                                   const float* __restrict__ lW1,
                                                   const float* __restrict__ lb1,
                                                   const float* __restrict__ lW2,
                                                   const float* __restrict__ lb2,
                                                   const int* __restrict__ labels,
                                                   const float* __restrict__ pmsum,
                                                   float* __restrict__ p,
                                                   float* __restrict__ loss,
                                                   int N, int ZR) {
  int lane = threadIdx.x & 63;
  int cl = threadIdx.x >> 2;
  int c = blockIdx.x * 64 + cl;
  int l4 = lane & 3;
  int qbase = lane & 60;
  bool ok = c < N;
  int s = 0, e = 0;
  float dc = 0.f;
  uint4 svr = {0u, 0u, 0u, 0u};
  if (ok) {
    s = offsets[c]; e = offsets[c + 1];
    dc = dinv[c];
    svr = *(const uint4*)(A8in + ((size_t)c << 6) + l4 * 16);
  }
  GATHER_CORE(A8in, ZR)
  float contrib = 0.f;
  {
    a0 += __builtin_amdgcn_cvt_pk_f32_fp8((int)svr.x, false);
    a1 += __builtin_amdgcn_cvt_pk_f32_fp8((int)svr.x, true);
    a2 += __builtin_amdgcn_cvt_pk_f32_fp8((int)svr.y, false);
    a3 += __builtin_amdgcn_cvt_pk_f32_fp8((int)svr.y, true);
    a4 += __builtin_amdgcn_cvt_pk_f32_fp8((int)svr.z, false);
    a5 += __builtin_amdgcn_cvt_pk_f32_fp8((int)svr.z, true);
    a6 += __builtin_amdgcn_cvt_pk_f32_fp8((int)svr.w, false);
    a7 += __builtin_amdgcn_cvt_pk_f32_fp8((int)svr.w, true);
    float accf[16] = {a0[0],a0[1],a1[0],a1[1],a2[0],a2[1],a3[0],a3[1],
                      a4[0],a4[1],a5[0],a5[1],a6[0],a6[1],a7[0],a7[1]};
    const float* bp = bias + l4 * 16;
    float hq[16];
#pragma unroll
    for (int q = 0; q < 16; ++q) {
      float v = fmaf(accf[q], dc, bp[q]);
      hq[q] = v > 0.f ? v : 0.f;
    }
    float acc8[8] = {0.f,0.f,0.f,0.f,0.f,0.f,0.f,0.f};
#pragma unroll
    for (int q = 0; q < 16; ++q) {
      int k = l4 * 16 + q;
#pragma unroll
      for (int j = 0; j < 8; ++j) acc8[j] = fmaf(hq[q], lW1[k * 8 + j], acc8[j]);
    }
#pragma unroll
    for (int j = 0; j < 8; ++j) {
      acc8[j] += __shfl_xor(acc8[j], 1);
      acc8[j] += __shfl_xor(acc8[j], 2);
    }
    if (ok && l4 == 0) {
      float sv = lb2[0];
#pragma unroll
      for (int j = 0; j < 8; ++j) {
        float a = acc8[j] + lb1[j];
        a = a > 0.f ? a : 0.f;
        sv = fmaf(a, lW2[j], sv);
      }
      float pv = 1.0f / (1.0f + expf(-sv));
      p[c] = pv;
      float pm = *pmsum / (float)N;
      float y = (float)labels[c];
      float w = y * (1.f - pm) + (1.f - y) * pm;
      float pc = fminf(fmaxf(pv, 1e-7f), 1.f - 1e-7f);
      float bce = -(y * logf(pc) + (1.f - y) * logf(1.f - pc));
      contrib = w * bce / (float)N;
    }
  }
#pragma unroll
  for (int o = 32; o > 0; o >>= 1) contrib += __shfl_down(contrib, o);
  __shared__ float sh[4];
  int wv = threadIdx.x >> 6;
  if (lane == 0) sh[wv] = contrib;
  __syncthreads();
  if (threadIdx.x == 0) atomicAdd(loss, sh[0] + sh[1] + sh[2] + sh[3]);
}

// ---------------- launch ----------------

extern "C" void kernel_launch(void* const* d_in, const int* in_sizes, int n_in,
                              void* d_out, int out_size, void* d_ws, size_t ws_size,
                              hipStream_t stream) {
  const float* x      = (const float*)d_in[0];
  const int*   ei     = (const int*)d_in[1];
  const int*   labels = (const int*)d_in[2];
  const float* W1 = (const float*)d_in[3];
  const float* b1 = (const float*)d_in[4];
  const float* W2 = (const float*)d_in[5];
  const float* b2 = (const float*)d_in[6];
  const float* W3 = (const float*)d_in[7];
  const float* b3 = (const float*)d_in[8];
  const float* lW1 = (const float*)d_in[9];
  const float* lb1 = (const float*)d_in[10];
  const float* lW2 = (const float*)d_in[11];
  const float* lb2 = (const float*)d_in[12];

  int N = in_sizes[2];            // labels: [N,1]
  int E = in_sizes[1] / 2;        // edge_index: [2,E]
  const int* rows = ei;           // sources
  const int* cols = ei + E;       // targets (aggregation)

  int Npad = (N + 63) & ~63;
  int NBUCK = (N + 255) >> 8;               // 256-node buckets
  int totalH = NBUCK * NBLK;                // histogram entries
  int nb2 = (totalH + 255) / 256;

  // workspace layout: A8 buffers have one extra zero-row at index Npad (gather clamp)
  size_t a8stride = (size_t)Npad * 64 + 256;
  char* ws = (char*)d_ws;
  unsigned char*  A8a = (unsigned char*)ws;
  unsigned char*  A8b = (unsigned char*)(ws + a8stride);
  unsigned short* Wt1 = (unsigned short*)(ws + (size_t)Npad * 192); // 64*128
  unsigned short* Wt2 = Wt1 + 64 * 128;                 // 64*64
  unsigned short* Wt3 = Wt2 + 64 * 64;                  // 64*64
  float* dinv     = (float*)(Wt3 + 64 * 64);            // N
  int*   offsets  = (int*)(dinv + N);                   // N+1
  int*   histG    = offsets + N + 1;                    // NBLK*NBUCK
  int*   scanned  = histG + totalH;                     // NBLK*NBUCK
  unsigned int* packed = (unsigned int*)(scanned + totalH);  // E
  int*   sorted   = (int*)(packed + E);                 // E
  int*   partials = sorted + E;                         // nb2
  float* pmsum    = (float*)(partials + nb2);           // 1
  float* labelsum = pmsum + 1;                          // NBLK

  float* loss = (float*)d_out;
  float* p    = (float*)d_out + 1;

  int aggBlocks  = (N + 63) / 64;
  int ZR = Npad;                   // zero-row index

  // ---- atomic-free CSR build (+ Wt transpose, zero-rows & label-sum folded into hist) ----
  hist_kernel<<<NBLK, 256, 0, stream>>>(cols, histG, labels, labelsum,
                                        W1, W2, W3, Wt1, Wt2, Wt3,
                                        A8a + (size_t)Npad * 64, A8b + (size_t)Npad * 64,
                                        E, N, NBUCK);
  scan_partials_t<<<nb2, 256, 0, stream>>>(histG, partials, totalH, NBUCK);
  scan_block<<<1, 256, 0, stream>>>(partials, nb2, loss, labelsum, pmsum);
  scan_final_t<<<nb2, 256, 0, stream>>>(histG, partials, scanned, totalH, NBUCK);
  scatter_kernel<<<NBLK, 256, 0, stream>>>(rows, cols, scanned, packed, E, NBUCK);

  // ---- CSR finalize + layer-1 GEMM fused (dinv is bucket-local) ----
  csr_finalize_gemm1<<<NBUCK, 1024, 0, stream>>>(packed, scanned, sorted, offsets, dinv,
                                                 x, Wt1, A8a, N, E, NBUCK);

  // ---- fused layers: agg1+gemm2, agg2+gemm3, agg3+head ----
  agg_gemm<<<aggBlocks, 256, 0, stream>>>(A8a, offsets, sorted, dinv, b1, Wt2, A8b, N, ZR);
  agg_gemm<<<aggBlocks, 256, 0, stream>>>(A8b, offsets, sorted, dinv, b2, Wt3, A8a, N, ZR);
  agg_head<<<aggBlocks, 256, 0, stream>>>(A8a, offsets, sorted, dinv, b3,
                                          lW1, lb1, lW2, lb2, labels, pmsum, p, loss, N, ZR);
}